// Round 7
// baseline (164.667 us; speedup 1.0000x reference)
//
#include <hip/hip_runtime.h>
#include <math.h>

// Problem constants
#define Bn   4
#define Cc   64
#define Hh   128
#define Ww   128
#define Oo   64
#define HW   16384
#define NPAR 27

// Workspace layout (float offsets)
#define WB2_OFF 0        // bf16 AT2[t][cc][mt2][lane64][8] = 36864 shorts
#define WB_OFF  18432    // bf16 ATd[t][h][mt4][lane64][8]  = 36864 shorts
#define PAR_OFF 36864    // f32 par[B][27][HW]

typedef __attribute__((ext_vector_type(8))) short bf16x8;
typedef __attribute__((ext_vector_type(4))) short s16x4;
typedef __attribute__((ext_vector_type(4))) float f32x4;
typedef __attribute__((ext_vector_type(2), aligned(4))) float f32x2u;

__device__ __forceinline__ short f2bf(float f) {
    unsigned u = __builtin_bit_cast(unsigned, f);
    u += 0x7FFFu + ((u >> 16) & 1u);        // RNE
    return (short)(u >> 16);
}

// ---------------------------------------------------------------------------
// prep: pre-transpose weights into MFMA A-fragment order (coalesced dwordx4
// reads in the main kernels). K reordered tap-major; see r4 comment.
// ---------------------------------------------------------------------------
__global__ void prep_weights(const float* __restrict__ w_off,
                             const float* __restrict__ w_mod,
                             const float* __restrict__ w_reg,
                             float* __restrict__ ws) {
    int i = blockIdx.x * 256 + threadIdx.x;
    short* at2 = (short*)(ws + WB2_OFF);
    short* atd = (short*)(ws + WB_OFF);
    if (i < 36864) {
        int j = i & 7, l = (i >> 3) & 63, mt = (i >> 9) & 1, cc = (i >> 10) & 3, t = i >> 12;
        int lm = l & 15, quad = l >> 4;
        int row = mt * 16 + lm;
        int c = cc * 32 + quad * 8 + j;
        float v = 0.f;
        if (row < 18)      v = w_off[row * 1152 + c * 9 + t];
        else if (row < 27) v = w_mod[(row - 18) * 1152 + c * 9 + t];
        at2[i] = f2bf(v);
    } else if (i < 73728) {
        int e = i - 36864;
        int j = e & 7, l = (e >> 3) & 63, mt = (e >> 9) & 3, h = (e >> 11) & 1, t = e >> 12;
        int lm = l & 15, quad = l >> 4;
        int o = mt * 16 + lm;
        int c = h * 32 + quad * 8 + j;
        atd[e] = f2bf(w_reg[o * 576 + c * 9 + t]);
    }
}

// ---------------------------------------------------------------------------
// conv_mfma (unchanged from r4): barrier-free direct conv, bf16 channel-inner
// window [pos][128ch+8], one ds_read_b128 per B-fragment, coalesced A.
// 39.2KB LDS -> 4 blocks/CU.
// ---------------------------------------------------------------------------
#define CPSTR 136   // bf16 elems per position: 128 ch + 8 pad

__global__ __launch_bounds__(256, 4)
void conv_mfma(const float* __restrict__ x, const float* __restrict__ g,
               const float* __restrict__ ws_,
               const float* __restrict__ b_off, const float* __restrict__ b_mod,
               float* __restrict__ parw) {
    __shared__ __align__(16) short Wd[144 * CPSTR];   // 39168 B

    const int tid = threadIdx.x;
    const int l = tid & 63, lm = l & 15, quad = l >> 4;
    const int w = __builtin_amdgcn_readfirstlane(tid >> 6);   // wave = pixel row
    const int b = blockIdx.z;
    const int ho0 = blockIdx.y * 4, wo0 = blockIdx.x * 16;
    const int row_base = ho0 - 1;     // may be -1: halo rows zero-filled
    const int col_base = wo0 - 4;     // 4-aligned; halo cols zero-filled

    const short* at2 = (const short*)(ws_ + WB2_OFF);
    const float* xb = x + ((size_t)(b * Cc) << 14);
    const float* gb = g + ((size_t)(b * Cc) << 14);

    for (int s = tid; s < 1152; s += 256) {
        int pq = s >> 5, cq = s & 31;
        int r = pq / 6, c4 = (pq - r * 6) * 4;
        int row = row_base + r, col = col_base + c4;
        bool ok = ((unsigned)row < 128u) && ((unsigned)col < 128u);
        f32x4 v0, v1, v2, v3;
        {
            int ch = cq * 4;
            const float* p0 = (ch < Cc) ? (xb + ((size_t)ch << 14)) : (gb + ((size_t)(ch - Cc) << 14));
            const float* p1 = (ch + 1 < Cc) ? (xb + ((size_t)(ch + 1) << 14)) : (gb + ((size_t)(ch + 1 - Cc) << 14));
            const float* p2 = (ch + 2 < Cc) ? (xb + ((size_t)(ch + 2) << 14)) : (gb + ((size_t)(ch + 2 - Cc) << 14));
            const float* p3 = (ch + 3 < Cc) ? (xb + ((size_t)(ch + 3) << 14)) : (gb + ((size_t)(ch + 3 - Cc) << 14));
            f32x4 zz = {0.f, 0.f, 0.f, 0.f};
            size_t off = ((size_t)(row << 7) + col);
            v0 = ok ? *(const f32x4*)(p0 + off) : zz;
            v1 = ok ? *(const f32x4*)(p1 + off) : zz;
            v2 = ok ? *(const f32x4*)(p2 + off) : zz;
            v3 = ok ? *(const f32x4*)(p3 + off) : zz;
        }
#pragma unroll
        for (int p = 0; p < 4; p++) {
            s16x4 o4 = { f2bf(v0[p]), f2bf(v1[p]), f2bf(v2[p]), f2bf(v3[p]) };
            *(s16x4*)&Wd[(r * 24 + c4 + p) * CPSTR + cq * 4] = o4;
        }
    }
    __syncthreads();   // the ONLY barrier

    f32x4 acc0 = {0.f, 0.f, 0.f, 0.f}, acc1 = {0.f, 0.f, 0.f, 0.f};
#pragma unroll
    for (int t = 0; t < 9; t++) {
        int dy = t / 3, dx = t - dy * 3;
        int pos = (w + dy) * 24 + (lm + dx + 3);    // in-window coords, no masks
#pragma unroll
        for (int cc = 0; cc < 4; cc++) {
            bf16x8 bfr = *(const bf16x8*)&Wd[pos * CPSTR + cc * 32 + quad * 8];
            bf16x8 a0 = *(const bf16x8*)(at2 + t * 4096 + cc * 1024 + l * 8);
            bf16x8 a1 = *(const bf16x8*)(at2 + t * 4096 + cc * 1024 + 512 + l * 8);
            acc0 = __builtin_amdgcn_mfma_f32_16x16x32_bf16(a0, bfr, acc0, 0, 0, 0);
            acc1 = __builtin_amdgcn_mfma_f32_16x16x32_bf16(a1, bfr, acc1, 0, 0, 0);
        }
    }

    // Epilogue: D[row j][col lm] -> par channels, fused bias/coords/sigmoid
    const int ho = ho0 + w, wo = wo0 + lm;
    const int pix = (ho << 7) + wo;
    float* par = parw + (size_t)b * NPAR * HW + pix;
#pragma unroll
    for (int mt = 0; mt < 2; mt++) {
        f32x4 a = mt ? acc1 : acc0;
#pragma unroll
        for (int reg = 0; reg < 4; reg++) {
            int j = mt * 16 + quad * 4 + reg;
            float v = a[reg];
            if (j < 18) {
                int k = j >> 1;
                float vb = v + b_off[j];
                if (j & 1) par[(size_t)(9 + k) * HW] = vb + (float)(k - (k / 3) * 3 + wo - 1);
                else       par[(size_t)k * HW]       = vb + (float)(k / 3 + ho - 1);
            } else if (j < 27) {
                int k = j - 18;
                par[(size_t)(18 + k) * HW] = 2.f / (1.f + __expf(-(v + b_mod[k])));
            }
        }
    }
}

// ---------------------------------------------------------------------------
// deform_mfma round 7: per-tap pipeline + per-lane fallback.
// r6 landed 43.6us with VGPR=64, VALU 27%, Mfma 3.8%: the stall is the
// un-overlapped per-tap chain (par load ~200cy -> params -> 8 ds_reads
// ~120cy -> blend -> MFMA) x18, nothing in flight across taps.
// Changes: (1) block-wide fast/slow vote (27-load prologue + duplicated
// slow path, the structure that spilled r5) replaced by a PER-LANE
// fallback inside corner-load: LDS if in-window else exec-masked global
// gather (execz-skipped when all lanes in). (2) distance-1 software
// pipeline over taps: tap t+1's par loads + 8 corner ds_read_b128 are
// issued before tap t's blend+MFMA (2 taps = ~64 VGPR in flight; SSA
// rotation via fully-unrolled constant-index arrays -- no cross-barrier
// live arrays, unlike r5). Corner math identical -> numerics unchanged.
// ---------------------------------------------------------------------------
#define DPSTR 36   // f32 per position: 32 ch + 4 pad

struct TapP {
    float wa0, wb0, wa1, wb1;
    int ia, ib, gx0, gx1;
    bool in;
};

__device__ __forceinline__ TapP tap_params(const float* __restrict__ par, int pix, int k,
                                           int rb, int cb) {
    float py = par[(size_t)k * HW + pix];
    float px = par[(size_t)(9 + k) * HW + pix];
    float m  = par[(size_t)(18 + k) * HW + pix];
    float fy = floorf(py), fx = floorf(px);
    int y0 = (int)fy, x0 = (int)fx;
    int y1 = y0 + 1;
    float wy1 = py - fy, wx1 = px - fx;
    float wy0 = 1.f - wy1, wx0 = 1.f - wx1;
    bool vy0 = (unsigned)y0 < 128u, vy1 = (unsigned)y1 < 128u;
    bool vx0 = (unsigned)x0 < 128u, vx1 = (unsigned)(x0 + 1) < 128u;
    int cy0 = min(max(y0, 0), 127), cy1 = min(max(y1, 0), 127);
    int bx2 = min(max(x0, 0), 126);
    bool sel_lo = (x0 < 0), sel_hi = (x0 > 126);
    float w00 = (vy0 && vx0) ? wy0 * wx0 * m : 0.f;
    float w01 = (vy0 && vx1) ? wy0 * wx1 * m : 0.f;
    float w10 = (vy1 && vx0) ? wy1 * wx0 * m : 0.f;
    float w11 = (vy1 && vx1) ? wy1 * wx1 * m : 0.f;
    TapP r;
    // fold boundary handling into pair weights: wa->[bx2], wb->[bx2+1]
    r.wa0 = sel_lo ? w01 : (sel_hi ? 0.f : w00);
    r.wb0 = sel_hi ? w00 : (sel_lo ? 0.f : w01);
    r.wa1 = sel_lo ? w11 : (sel_hi ? 0.f : w10);
    r.wb1 = sel_hi ? w10 : (sel_lo ? 0.f : w11);
    int ty0 = cy0 - rb, ty1 = cy1 - rb, tx = bx2 - cb;
    r.ia = ty0 * 24 + tx;
    r.ib = ty1 * 24 + tx;
    r.gx0 = (cy0 << 7) + bx2;
    r.gx1 = (cy1 << 7) + bx2;
    r.in = ((unsigned)ty0 <= 9u) && ((unsigned)ty1 <= 9u) && ((unsigned)tx <= 22u);
    return r;
}

// Corner layout: c[hf*4+0]=p00, +1=p01(x+1), +2=p10(y+1), +3=p11; hf=ch half-quad
__device__ __forceinline__ void load_corners(const TapP P, const float* Xw,
                                             const float* __restrict__ xb,
                                             int h, int quad, f32x4* c) {
    if (P.in) {
        const float* pa = Xw + P.ia * DPSTR + quad * 8;
        const float* pb = Xw + P.ib * DPSTR + quad * 8;
        c[0] = *(const f32x4*)(pa);
        c[1] = *(const f32x4*)(pa + DPSTR);
        c[2] = *(const f32x4*)(pb);
        c[3] = *(const f32x4*)(pb + DPSTR);
        c[4] = *(const f32x4*)(pa + 4);
        c[5] = *(const f32x4*)(pa + DPSTR + 4);
        c[6] = *(const f32x4*)(pb + 4);
        c[7] = *(const f32x4*)(pb + DPSTR + 4);
    } else {
        // rare per-lane fallback: global bilinear corner pairs
#pragma unroll
        for (int hf = 0; hf < 2; hf++)
#pragma unroll
            for (int j = 0; j < 4; j++) {
                int cch = h * 32 + quad * 8 + hf * 4 + j;
                const float* xc = xb + ((size_t)cch << 14);
                f32x2u q0 = *(const f32x2u*)(xc + P.gx0);
                f32x2u q1 = *(const f32x2u*)(xc + P.gx1);
                c[hf * 4 + 0][j] = q0.x;
                c[hf * 4 + 1][j] = q0.y;
                c[hf * 4 + 2][j] = q1.x;
                c[hf * 4 + 3][j] = q1.y;
            }
    }
}

__global__ __launch_bounds__(256, 4)
void deform_mfma(const float* __restrict__ x, const float* __restrict__ ws_,
                 const float* __restrict__ par_base, float* __restrict__ out) {
    __shared__ __align__(16) float Xw[240 * DPSTR];   // 34560 B

    const int tid = threadIdx.x;
    const int l = tid & 63, lm = l & 15, quad = l >> 4;
    const int w = __builtin_amdgcn_readfirstlane(tid >> 6);   // wave = pixel row
    const int b = blockIdx.z;

    const int ho0 = blockIdx.y * 4, wo0 = blockIdx.x * 16;
    const int rb = min(max(ho0 - 3, 0), 128 - 10);
    const int cb = min(max(wo0 - 4, 0), 128 - 24);    // 4-aligned

    const float* par = par_base + (size_t)b * NPAR * HW;
    const short* atd = (const short*)(ws_ + WB_OFF);
    const float* xb  = x + ((size_t)(b * Cc) << 14);

    const int pix = ((ho0 + w) << 7) + (wo0 + lm);    // lane's own pixel

    // window stage: 60 pos-quads x 8 ch-quads; 4 f32x4 loads + transpose +
    // 4 f32x4 ds_writes, ch-inner. All positions in-image (bases clamped).
    auto STAGE = [&](int h) {
        for (int s = tid; s < 480; s += 256) {
            int pq = s >> 3, cq = s & 7;
            int r = pq / 6, c4 = (pq - r * 6) * 4;
            size_t off = (size_t)((rb + r) << 7) + cb + c4;
            f32x4 v0 = *(const f32x4*)(xb + ((size_t)(h * 32 + cq * 4 + 0) << 14) + off);
            f32x4 v1 = *(const f32x4*)(xb + ((size_t)(h * 32 + cq * 4 + 1) << 14) + off);
            f32x4 v2 = *(const f32x4*)(xb + ((size_t)(h * 32 + cq * 4 + 2) << 14) + off);
            f32x4 v3 = *(const f32x4*)(xb + ((size_t)(h * 32 + cq * 4 + 3) << 14) + off);
#pragma unroll
            for (int p = 0; p < 4; p++) {
                f32x4 o4 = { v0[p], v1[p], v2[p], v3[p] };
                *(f32x4*)&Xw[(r * 24 + c4 + p) * DPSTR + cq * 4] = o4;
            }
        }
    };

    STAGE(0);
    __syncthreads();

    f32x4 acc[4];
#pragma unroll
    for (int mt = 0; mt < 4; mt++) acc[mt] = (f32x4){0.f, 0.f, 0.f, 0.f};

    auto T_LOOP = [&](int h) {
        TapP P = tap_params(par, pix, 0, rb, cb);
        f32x4 cur[8];
        load_corners(P, Xw, xb, h, quad, cur);
#pragma unroll
        for (int t = 0; t < 9; t++) {
            TapP Pn;
            f32x4 nxt[8];
            if (t < 8) {                                   // issue tap t+1 early
                Pn = tap_params(par, pix, t + 1, rb, cb);
                load_corners(Pn, Xw, xb, h, quad, nxt);
            }
            union { short s8[8]; bf16x8 v; } u;
#pragma unroll
            for (int hf = 0; hf < 2; hf++)
#pragma unroll
                for (int j = 0; j < 4; j++)
                    u.s8[hf * 4 + j] = f2bf(P.wa0 * cur[hf * 4 + 0][j] + P.wb0 * cur[hf * 4 + 1][j] +
                                            P.wa1 * cur[hf * 4 + 2][j] + P.wb1 * cur[hf * 4 + 3][j]);
#pragma unroll
            for (int mt = 0; mt < 4; mt++) {
                bf16x8 a = *(const bf16x8*)(atd + t * 4096 + h * 2048 + mt * 512 + l * 8);
                acc[mt] = __builtin_amdgcn_mfma_f32_16x16x32_bf16(a, u.v, acc[mt], 0, 0, 0);
            }
            if (t < 8) {                                   // SSA rotate
                P = Pn;
#pragma unroll
                for (int i = 0; i < 8; i++) cur[i] = nxt[i];
            }
        }
    };

    T_LOOP(0);
    __syncthreads();      // all waves done reading half 0
    STAGE(1);
    __syncthreads();
    T_LOOP(1);

    // Epilogue: D[row=quad*4+reg][col=lm]; o = mt*16+row, pixel = (ho0+w, wo0+lm)
    const int wo = wo0 + lm, ho = ho0 + w;
#pragma unroll
    for (int mt = 0; mt < 4; mt++) {
        float* op = out + ((size_t)(b * Oo + mt * 16 + quad * 4) << 14) + (ho << 7) + wo;
#pragma unroll
        for (int reg = 0; reg < 4; reg++)
            op[(size_t)reg << 14] = acc[mt][reg];
    }
}

// ---------------------------------------------------------------------------
extern "C" void kernel_launch(void* const* d_in, const int* in_sizes, int n_in,
                              void* d_out, int out_size, void* d_ws, size_t ws_size,
                              hipStream_t stream) {
    const float* x     = (const float*)d_in[0];
    const float* guide = (const float*)d_in[1];
    const float* w_off = (const float*)d_in[2];
    const float* b_off = (const float*)d_in[3];
    const float* w_mod = (const float*)d_in[4];
    const float* b_mod = (const float*)d_in[5];
    const float* w_reg = (const float*)d_in[6];
    float* out = (float*)d_out;
    float* ws  = (float*)d_ws;

    hipLaunchKernelGGL(prep_weights, dim3((73728 + 255) / 256), dim3(256),
                       0, stream, w_off, w_mod, w_reg, ws);
    hipLaunchKernelGGL(conv_mfma, dim3(Ww / 16, Hh / 4, Bn), dim3(256),
                       0, stream, x, guide, ws, b_off, b_mod, ws + PAR_OFF);
    hipLaunchKernelGGL(deform_mfma, dim3(Ww / 16, Hh / 4, Bn), dim3(256),
                       0, stream, x, ws, ws + PAR_OFF, out);
}

// Round 8
// 160.066 us; speedup vs baseline: 1.0287x; 1.0287x over previous
//
#include <hip/hip_runtime.h>
#include <math.h>

// Problem constants
#define Bn   4
#define Cc   64
#define Hh   128
#define Ww   128
#define Oo   64
#define HW   16384
#define NPAR 27

// Workspace layout (float offsets)
#define WB2_OFF 0        // bf16 AT2[t][cc][mt2][lane64][8] = 36864 shorts
#define WB_OFF  18432    // bf16 ATd[t][h][mt4][lane64][8]  = 36864 shorts
#define PAR_OFF 36864    // f32 par[B][27][HW]

typedef __attribute__((ext_vector_type(8))) short bf16x8;
typedef __attribute__((ext_vector_type(4))) short s16x4;
typedef __attribute__((ext_vector_type(4))) float f32x4;
typedef __attribute__((ext_vector_type(2), aligned(4))) float f32x2u;

__device__ __forceinline__ short f2bf(float f) {
    unsigned u = __builtin_bit_cast(unsigned, f);
    u += 0x7FFFu + ((u >> 16) & 1u);        // RNE
    return (short)(u >> 16);
}

// ---------------------------------------------------------------------------
// prep: pre-transpose weights into MFMA A-fragment order (coalesced dwordx4
// reads in the main kernels). K reordered tap-major; see r4 comment.
// ---------------------------------------------------------------------------
__global__ void prep_weights(const float* __restrict__ w_off,
                             const float* __restrict__ w_mod,
                             const float* __restrict__ w_reg,
                             float* __restrict__ ws) {
    int i = blockIdx.x * 256 + threadIdx.x;
    short* at2 = (short*)(ws + WB2_OFF);
    short* atd = (short*)(ws + WB_OFF);
    if (i < 36864) {
        int j = i & 7, l = (i >> 3) & 63, mt = (i >> 9) & 1, cc = (i >> 10) & 3, t = i >> 12;
        int lm = l & 15, quad = l >> 4;
        int row = mt * 16 + lm;
        int c = cc * 32 + quad * 8 + j;
        float v = 0.f;
        if (row < 18)      v = w_off[row * 1152 + c * 9 + t];
        else if (row < 27) v = w_mod[(row - 18) * 1152 + c * 9 + t];
        at2[i] = f2bf(v);
    } else if (i < 73728) {
        int e = i - 36864;
        int j = e & 7, l = (e >> 3) & 63, mt = (e >> 9) & 3, h = (e >> 11) & 1, t = e >> 12;
        int lm = l & 15, quad = l >> 4;
        int o = mt * 16 + lm;
        int c = h * 32 + quad * 8 + j;
        atd[e] = f2bf(w_reg[o * 576 + c * 9 + t]);
    }
}

// ---------------------------------------------------------------------------
// conv_mfma (unchanged from r4): barrier-free direct conv, bf16 channel-inner
// window [pos][128ch+8], one ds_read_b128 per B-fragment, coalesced A.
// 39.2KB LDS -> 4 blocks/CU.
// ---------------------------------------------------------------------------
#define CPSTR 136   // bf16 elems per position: 128 ch + 8 pad

__global__ __launch_bounds__(256, 4)
void conv_mfma(const float* __restrict__ x, const float* __restrict__ g,
               const float* __restrict__ ws_,
               const float* __restrict__ b_off, const float* __restrict__ b_mod,
               float* __restrict__ parw) {
    __shared__ __align__(16) short Wd[144 * CPSTR];   // 39168 B

    const int tid = threadIdx.x;
    const int l = tid & 63, lm = l & 15, quad = l >> 4;
    const int w = __builtin_amdgcn_readfirstlane(tid >> 6);   // wave = pixel row
    const int b = blockIdx.z;
    const int ho0 = blockIdx.y * 4, wo0 = blockIdx.x * 16;
    const int row_base = ho0 - 1;     // may be -1: halo rows zero-filled
    const int col_base = wo0 - 4;     // 4-aligned; halo cols zero-filled

    const short* at2 = (const short*)(ws_ + WB2_OFF);
    const float* xb = x + ((size_t)(b * Cc) << 14);
    const float* gb = g + ((size_t)(b * Cc) << 14);

    for (int s = tid; s < 1152; s += 256) {
        int pq = s >> 5, cq = s & 31;
        int r = pq / 6, c4 = (pq - r * 6) * 4;
        int row = row_base + r, col = col_base + c4;
        bool ok = ((unsigned)row < 128u) && ((unsigned)col < 128u);
        f32x4 v0, v1, v2, v3;
        {
            int ch = cq * 4;
            const float* p0 = (ch < Cc) ? (xb + ((size_t)ch << 14)) : (gb + ((size_t)(ch - Cc) << 14));
            const float* p1 = (ch + 1 < Cc) ? (xb + ((size_t)(ch + 1) << 14)) : (gb + ((size_t)(ch + 1 - Cc) << 14));
            const float* p2 = (ch + 2 < Cc) ? (xb + ((size_t)(ch + 2) << 14)) : (gb + ((size_t)(ch + 2 - Cc) << 14));
            const float* p3 = (ch + 3 < Cc) ? (xb + ((size_t)(ch + 3) << 14)) : (gb + ((size_t)(ch + 3 - Cc) << 14));
            f32x4 zz = {0.f, 0.f, 0.f, 0.f};
            size_t off = ((size_t)(row << 7) + col);
            v0 = ok ? *(const f32x4*)(p0 + off) : zz;
            v1 = ok ? *(const f32x4*)(p1 + off) : zz;
            v2 = ok ? *(const f32x4*)(p2 + off) : zz;
            v3 = ok ? *(const f32x4*)(p3 + off) : zz;
        }
#pragma unroll
        for (int p = 0; p < 4; p++) {
            s16x4 o4 = { f2bf(v0[p]), f2bf(v1[p]), f2bf(v2[p]), f2bf(v3[p]) };
            *(s16x4*)&Wd[(r * 24 + c4 + p) * CPSTR + cq * 4] = o4;
        }
    }
    __syncthreads();   // the ONLY barrier

    f32x4 acc0 = {0.f, 0.f, 0.f, 0.f}, acc1 = {0.f, 0.f, 0.f, 0.f};
#pragma unroll
    for (int t = 0; t < 9; t++) {
        int dy = t / 3, dx = t - dy * 3;
        int pos = (w + dy) * 24 + (lm + dx + 3);    // in-window coords, no masks
#pragma unroll
        for (int cc = 0; cc < 4; cc++) {
            bf16x8 bfr = *(const bf16x8*)&Wd[pos * CPSTR + cc * 32 + quad * 8];
            bf16x8 a0 = *(const bf16x8*)(at2 + t * 4096 + cc * 1024 + l * 8);
            bf16x8 a1 = *(const bf16x8*)(at2 + t * 4096 + cc * 1024 + 512 + l * 8);
            acc0 = __builtin_amdgcn_mfma_f32_16x16x32_bf16(a0, bfr, acc0, 0, 0, 0);
            acc1 = __builtin_amdgcn_mfma_f32_16x16x32_bf16(a1, bfr, acc1, 0, 0, 0);
        }
    }

    // Epilogue: D[row j][col lm] -> par channels, fused bias/coords/sigmoid
    const int ho = ho0 + w, wo = wo0 + lm;
    const int pix = (ho << 7) + wo;
    float* par = parw + (size_t)b * NPAR * HW + pix;
#pragma unroll
    for (int mt = 0; mt < 2; mt++) {
        f32x4 a = mt ? acc1 : acc0;
#pragma unroll
        for (int reg = 0; reg < 4; reg++) {
            int j = mt * 16 + quad * 4 + reg;
            float v = a[reg];
            if (j < 18) {
                int k = j >> 1;
                float vb = v + b_off[j];
                if (j & 1) par[(size_t)(9 + k) * HW] = vb + (float)(k - (k / 3) * 3 + wo - 1);
                else       par[(size_t)k * HW]       = vb + (float)(k / 3 + ho - 1);
            } else if (j < 27) {
                int k = j - 18;
                par[(size_t)(18 + k) * HW] = 2.f / (1.f + __expf(-(v + b_mod[k])));
            }
        }
    }
}

// ---------------------------------------------------------------------------
// deform_mfma round 8: r7's distance-1 tap pipeline, with the two codegen
// diseases fixed. r7 spilled (WRITE 16->42MB, VGPR pinned 64): hipcc's
// occupancy heuristic targeted 8 waves/EU (64 VGPR) despite launch_bounds
// min=4 allowing 128, and the if/else in-window branch duplicated both
// corner paths in the 18x-unrolled loop. Fixes: (1) amdgpu_waves_per_eu(4,4)
// pins exactly 4 waves/EU -> honest 128-VGPR budget; (2) corner load is an
// UNCONDITIONAL clamped-LDS read (clamp is a no-op for in-window taps)
// followed by a rare exec-masked global fix-up -- no else-path duplication.
// Corner math identical -> numerics unchanged.
// ---------------------------------------------------------------------------
#define DPSTR 36   // f32 per position: 32 ch + 4 pad

struct TapP {
    float wa0, wb0, wa1, wb1;
    int ia, ib, gx0, gx1;
    bool in;
};

__device__ __forceinline__ TapP tap_params(const float* __restrict__ par, int pix, int k,
                                           int rb, int cb) {
    float py = par[(size_t)k * HW + pix];
    float px = par[(size_t)(9 + k) * HW + pix];
    float m  = par[(size_t)(18 + k) * HW + pix];
    float fy = floorf(py), fx = floorf(px);
    int y0 = (int)fy, x0 = (int)fx;
    int y1 = y0 + 1;
    float wy1 = py - fy, wx1 = px - fx;
    float wy0 = 1.f - wy1, wx0 = 1.f - wx1;
    bool vy0 = (unsigned)y0 < 128u, vy1 = (unsigned)y1 < 128u;
    bool vx0 = (unsigned)x0 < 128u, vx1 = (unsigned)(x0 + 1) < 128u;
    int cy0 = min(max(y0, 0), 127), cy1 = min(max(y1, 0), 127);
    int bx2 = min(max(x0, 0), 126);
    bool sel_lo = (x0 < 0), sel_hi = (x0 > 126);
    float w00 = (vy0 && vx0) ? wy0 * wx0 * m : 0.f;
    float w01 = (vy0 && vx1) ? wy0 * wx1 * m : 0.f;
    float w10 = (vy1 && vx0) ? wy1 * wx0 * m : 0.f;
    float w11 = (vy1 && vx1) ? wy1 * wx1 * m : 0.f;
    TapP r;
    // fold boundary handling into pair weights: wa->[bx2], wb->[bx2+1]
    r.wa0 = sel_lo ? w01 : (sel_hi ? 0.f : w00);
    r.wb0 = sel_hi ? w00 : (sel_lo ? 0.f : w01);
    r.wa1 = sel_lo ? w11 : (sel_hi ? 0.f : w10);
    r.wb1 = sel_hi ? w10 : (sel_lo ? 0.f : w11);
    int ty0 = cy0 - rb, ty1 = cy1 - rb, tx = bx2 - cb;
    r.ia = ty0 * 24 + tx;
    r.ib = ty1 * 24 + tx;
    r.gx0 = (cy0 << 7) + bx2;
    r.gx1 = (cy1 << 7) + bx2;
    r.in = ((unsigned)ty0 <= 9u) && ((unsigned)ty1 <= 9u) && ((unsigned)tx <= 22u);
    return r;
}

// Corner layout: c[hf*4+0]=p00, +1=p01(x+1), +2=p10(y+1), +3=p11; hf=ch half-quad
__device__ __forceinline__ void lds_corners(const TapP& P, const float* Xw,
                                            int quad, f32x4* c) {
    int ia = min(max(P.ia, 0), 238);   // no-op when in-window; keeps read in-bounds
    int ib = min(max(P.ib, 0), 238);
    const float* pa = Xw + ia * DPSTR + quad * 8;
    const float* pb = Xw + ib * DPSTR + quad * 8;
    c[0] = *(const f32x4*)(pa);
    c[1] = *(const f32x4*)(pa + DPSTR);
    c[2] = *(const f32x4*)(pb);
    c[3] = *(const f32x4*)(pb + DPSTR);
    c[4] = *(const f32x4*)(pa + 4);
    c[5] = *(const f32x4*)(pa + DPSTR + 4);
    c[6] = *(const f32x4*)(pb + 4);
    c[7] = *(const f32x4*)(pb + DPSTR + 4);
}

__device__ __forceinline__ void fix_corners(const TapP& P, const float* __restrict__ xb,
                                            int h, int quad, f32x4* c) {
    if (__builtin_expect(!P.in, 0)) {   // exec-masked rare patch, execz-skipped
#pragma unroll
        for (int hf = 0; hf < 2; hf++)
#pragma unroll
            for (int j = 0; j < 4; j++) {
                int cch = h * 32 + quad * 8 + hf * 4 + j;
                const float* xc = xb + ((size_t)cch << 14);
                f32x2u q0 = *(const f32x2u*)(xc + P.gx0);
                f32x2u q1 = *(const f32x2u*)(xc + P.gx1);
                c[hf * 4 + 0][j] = q0.x;
                c[hf * 4 + 1][j] = q0.y;
                c[hf * 4 + 2][j] = q1.x;
                c[hf * 4 + 3][j] = q1.y;
            }
    }
}

__global__ __attribute__((amdgpu_waves_per_eu(4, 4))) __launch_bounds__(256)
void deform_mfma(const float* __restrict__ x, const float* __restrict__ ws_,
                 const float* __restrict__ par_base, float* __restrict__ out) {
    __shared__ __align__(16) float Xw[240 * DPSTR];   // 34560 B

    const int tid = threadIdx.x;
    const int l = tid & 63, lm = l & 15, quad = l >> 4;
    const int w = __builtin_amdgcn_readfirstlane(tid >> 6);   // wave = pixel row
    const int b = blockIdx.z;

    const int ho0 = blockIdx.y * 4, wo0 = blockIdx.x * 16;
    const int rb = min(max(ho0 - 3, 0), 128 - 10);
    const int cb = min(max(wo0 - 4, 0), 128 - 24);    // 4-aligned

    const float* par = par_base + (size_t)b * NPAR * HW;
    const short* atd = (const short*)(ws_ + WB_OFF);
    const float* xb  = x + ((size_t)(b * Cc) << 14);

    const int pix = ((ho0 + w) << 7) + (wo0 + lm);    // lane's own pixel

    // window stage: 60 pos-quads x 8 ch-quads; 4 f32x4 loads + transpose +
    // 4 f32x4 ds_writes, ch-inner. All positions in-image (bases clamped).
    auto STAGE = [&](int h) {
        for (int s = tid; s < 480; s += 256) {
            int pq = s >> 3, cq = s & 7;
            int r = pq / 6, c4 = (pq - r * 6) * 4;
            size_t off = (size_t)((rb + r) << 7) + cb + c4;
            f32x4 v0 = *(const f32x4*)(xb + ((size_t)(h * 32 + cq * 4 + 0) << 14) + off);
            f32x4 v1 = *(const f32x4*)(xb + ((size_t)(h * 32 + cq * 4 + 1) << 14) + off);
            f32x4 v2 = *(const f32x4*)(xb + ((size_t)(h * 32 + cq * 4 + 2) << 14) + off);
            f32x4 v3 = *(const f32x4*)(xb + ((size_t)(h * 32 + cq * 4 + 3) << 14) + off);
#pragma unroll
            for (int p = 0; p < 4; p++) {
                f32x4 o4 = { v0[p], v1[p], v2[p], v3[p] };
                *(f32x4*)&Xw[(r * 24 + c4 + p) * DPSTR + cq * 4] = o4;
            }
        }
    };

    STAGE(0);
    __syncthreads();

    f32x4 acc[4];
#pragma unroll
    for (int mt = 0; mt < 4; mt++) acc[mt] = (f32x4){0.f, 0.f, 0.f, 0.f};

    auto T_LOOP = [&](int h) {
        TapP P = tap_params(par, pix, 0, rb, cb);
        f32x4 cur[8];
        lds_corners(P, Xw, quad, cur);
        fix_corners(P, xb, h, quad, cur);
#pragma unroll
        for (int t = 0; t < 9; t++) {
            TapP Pn;
            f32x4 nxt[8];
            if (t < 8) {                                   // issue tap t+1 early
                Pn = tap_params(par, pix, t + 1, rb, cb);
                lds_corners(Pn, Xw, quad, nxt);
                fix_corners(Pn, xb, h, quad, nxt);
            }
            union { short s8[8]; bf16x8 v; } u;
#pragma unroll
            for (int hf = 0; hf < 2; hf++)
#pragma unroll
                for (int j = 0; j < 4; j++)
                    u.s8[hf * 4 + j] = f2bf(P.wa0 * cur[hf * 4 + 0][j] + P.wb0 * cur[hf * 4 + 1][j] +
                                            P.wa1 * cur[hf * 4 + 2][j] + P.wb1 * cur[hf * 4 + 3][j]);
#pragma unroll
            for (int mt = 0; mt < 4; mt++) {
                bf16x8 a = *(const bf16x8*)(atd + t * 4096 + h * 2048 + mt * 512 + l * 8);
                acc[mt] = __builtin_amdgcn_mfma_f32_16x16x32_bf16(a, u.v, acc[mt], 0, 0, 0);
            }
            if (t < 8) {                                   // SSA rotate
                P = Pn;
#pragma unroll
                for (int i = 0; i < 8; i++) cur[i] = nxt[i];
            }
        }
    };

    T_LOOP(0);
    __syncthreads();      // all waves done reading half 0
    STAGE(1);
    __syncthreads();
    T_LOOP(1);

    // Epilogue: D[row=quad*4+reg][col=lm]; o = mt*16+row, pixel = (ho0+w, wo0+lm)
    const int wo = wo0 + lm, ho = ho0 + w;
#pragma unroll
    for (int mt = 0; mt < 4; mt++) {
        float* op = out + ((size_t)(b * Oo + mt * 16 + quad * 4) << 14) + (ho << 7) + wo;
#pragma unroll
        for (int reg = 0; reg < 4; reg++)
            op[(size_t)reg << 14] = acc[mt][reg];
    }
}

// ---------------------------------------------------------------------------
extern "C" void kernel_launch(void* const* d_in, const int* in_sizes, int n_in,
                              void* d_out, int out_size, void* d_ws, size_t ws_size,
                              hipStream_t stream) {
    const float* x     = (const float*)d_in[0];
    const float* guide = (const float*)d_in[1];
    const float* w_off = (const float*)d_in[2];
    const float* b_off = (const float*)d_in[3];
    const float* w_mod = (const float*)d_in[4];
    const float* b_mod = (const float*)d_in[5];
    const float* w_reg = (const float*)d_in[6];
    float* out = (float*)d_out;
    float* ws  = (float*)d_ws;

    hipLaunchKernelGGL(prep_weights, dim3((73728 + 255) / 256), dim3(256),
                       0, stream, w_off, w_mod, w_reg, ws);
    hipLaunchKernelGGL(conv_mfma, dim3(Ww / 16, Hh / 4, Bn), dim3(256),
                       0, stream, x, guide, ws, b_off, b_mod, ws + PAR_OFF);
    hipLaunchKernelGGL(deform_mfma, dim3(Ww / 16, Hh / 4, Bn), dim3(256),
                       0, stream, x, ws, ws + PAR_OFF, out);
}

// Round 9
// 153.916 us; speedup vs baseline: 1.0699x; 1.0400x over previous
//
#include <hip/hip_runtime.h>
#include <math.h>

// Problem constants
#define Bn   4
#define Cc   64
#define Hh   128
#define Ww   128
#define Oo   64
#define HW   16384
#define NPAR 27

// Workspace layout (float offsets)
#define WB2_OFF 0        // bf16 AT2[t][cc][mt2][lane64][8] = 36864 shorts
#define WB_OFF  18432    // bf16 ATd[t][h][mt4][lane64][8]  = 36864 shorts

typedef __attribute__((ext_vector_type(8))) short bf16x8;
typedef __attribute__((ext_vector_type(4))) short s16x4;
typedef __attribute__((ext_vector_type(4))) float f32x4;
typedef __attribute__((ext_vector_type(2), aligned(4))) float f32x2u;

__device__ __forceinline__ short f2bf(float f) {
    unsigned u = __builtin_bit_cast(unsigned, f);
    u += 0x7FFFu + ((u >> 16) & 1u);        // RNE
    return (short)(u >> 16);
}

// ---------------------------------------------------------------------------
// prep: pre-transpose weights into MFMA A-fragment order (unchanged from r4).
// ---------------------------------------------------------------------------
__global__ void prep_weights(const float* __restrict__ w_off,
                             const float* __restrict__ w_mod,
                             const float* __restrict__ w_reg,
                             float* __restrict__ ws) {
    int i = blockIdx.x * 256 + threadIdx.x;
    short* at2 = (short*)(ws + WB2_OFF);
    short* atd = (short*)(ws + WB_OFF);
    if (i < 36864) {
        int j = i & 7, l = (i >> 3) & 63, mt = (i >> 9) & 1, cc = (i >> 10) & 3, t = i >> 12;
        int lm = l & 15, quad = l >> 4;
        int row = mt * 16 + lm;
        int c = cc * 32 + quad * 8 + j;
        float v = 0.f;
        if (row < 18)      v = w_off[row * 1152 + c * 9 + t];
        else if (row < 27) v = w_mod[(row - 18) * 1152 + c * 9 + t];
        at2[i] = f2bf(v);
    } else if (i < 73728) {
        int e = i - 36864;
        int j = e & 7, l = (e >> 3) & 63, mt = (e >> 9) & 3, h = (e >> 11) & 1, t = e >> 12;
        int lm = l & 15, quad = l >> 4;
        int o = mt * 16 + lm;
        int c = h * 32 + quad * 8 + j;
        atd[e] = f2bf(w_reg[o * 576 + c * 9 + t]);
    }
}

// ---------------------------------------------------------------------------
// FUSED kernel round 9. r0-r8 evidence: conv ~43us + deform ~43us, both
// latency-serialized (pipe-sum ~ wall, 16 waves/CU grid cap), deform's
// longest per-tap link = 3 par loads (200-900cy) x18. But par for tile
// (ho0,wo0) is produced by conv for EXACTLY the same pixels with the SAME
// wave=row/lm=col layout -> par never needs HBM. Fusion: conv phase -> 8
// transformed values/lane -> 27 __shfl to give each lane its pixel's 27
// params in registers (pr[27], all literal-indexed) -> deform phase with
// zero par loads. LDS: Wd (39.2KB) unioned with Xw (34.5KB) -> 39.2KB,
// 4 blocks/CU. Saves one dispatch + par's 14MB HBM round trip + the
// par-load latency links. Numerics bit-identical (par f32 regs vs f32 HBM).
// ---------------------------------------------------------------------------
#define CPSTR 136   // bf16 per conv pos: 128 ch + 8 pad
#define DPSTR 36    // f32 per deform pos: 32 ch + 4 pad

struct TapP {
    float wa0, wb0, wa1, wb1;
    int ia, ib, gx0, gx1;
    bool in;
};

__device__ __forceinline__ TapP tap_params_v(float py, float px, float m,
                                             int rb, int cb) {
    float fy = floorf(py), fx = floorf(px);
    int y0 = (int)fy, x0 = (int)fx;
    int y1 = y0 + 1;
    float wy1 = py - fy, wx1 = px - fx;
    float wy0 = 1.f - wy1, wx0 = 1.f - wx1;
    bool vy0 = (unsigned)y0 < 128u, vy1 = (unsigned)y1 < 128u;
    bool vx0 = (unsigned)x0 < 128u, vx1 = (unsigned)(x0 + 1) < 128u;
    int cy0 = min(max(y0, 0), 127), cy1 = min(max(y1, 0), 127);
    int bx2 = min(max(x0, 0), 126);
    bool sel_lo = (x0 < 0), sel_hi = (x0 > 126);
    float w00 = (vy0 && vx0) ? wy0 * wx0 * m : 0.f;
    float w01 = (vy0 && vx1) ? wy0 * wx1 * m : 0.f;
    float w10 = (vy1 && vx0) ? wy1 * wx0 * m : 0.f;
    float w11 = (vy1 && vx1) ? wy1 * wx1 * m : 0.f;
    TapP r;
    // fold boundary handling into pair weights: wa->[bx2], wb->[bx2+1]
    r.wa0 = sel_lo ? w01 : (sel_hi ? 0.f : w00);
    r.wb0 = sel_hi ? w00 : (sel_lo ? 0.f : w01);
    r.wa1 = sel_lo ? w11 : (sel_hi ? 0.f : w10);
    r.wb1 = sel_hi ? w10 : (sel_lo ? 0.f : w11);
    int ty0 = cy0 - rb, ty1 = cy1 - rb, tx = bx2 - cb;
    r.ia = ty0 * 24 + tx;
    r.ib = ty1 * 24 + tx;
    r.gx0 = (cy0 << 7) + bx2;
    r.gx1 = (cy1 << 7) + bx2;
    r.in = ((unsigned)ty0 <= 9u) && ((unsigned)ty1 <= 9u) && ((unsigned)tx <= 22u);
    return r;
}

// Corner layout: c[hf*4+0]=p00, +1=p01(x+1), +2=p10(y+1), +3=p11; hf=ch half-quad
__device__ __forceinline__ void lds_corners(const TapP& P, const float* Xw,
                                            int quad, f32x4* c) {
    int ia = min(max(P.ia, 0), 238);   // no-op when in-window
    int ib = min(max(P.ib, 0), 238);
    const float* pa = Xw + ia * DPSTR + quad * 8;
    const float* pb = Xw + ib * DPSTR + quad * 8;
    c[0] = *(const f32x4*)(pa);
    c[1] = *(const f32x4*)(pa + DPSTR);
    c[2] = *(const f32x4*)(pb);
    c[3] = *(const f32x4*)(pb + DPSTR);
    c[4] = *(const f32x4*)(pa + 4);
    c[5] = *(const f32x4*)(pa + DPSTR + 4);
    c[6] = *(const f32x4*)(pb + 4);
    c[7] = *(const f32x4*)(pb + DPSTR + 4);
}

__device__ __forceinline__ void fix_corners(const TapP& P, const float* __restrict__ xb,
                                            int h, int quad, f32x4* c) {
    if (__builtin_expect(!P.in, 0)) {   // exec-masked rare patch
#pragma unroll
        for (int hf = 0; hf < 2; hf++)
#pragma unroll
            for (int j = 0; j < 4; j++) {
                int cch = h * 32 + quad * 8 + hf * 4 + j;
                const float* xc = xb + ((size_t)cch << 14);
                f32x2u q0 = *(const f32x2u*)(xc + P.gx0);
                f32x2u q1 = *(const f32x2u*)(xc + P.gx1);
                c[hf * 4 + 0][j] = q0.x;
                c[hf * 4 + 1][j] = q0.y;
                c[hf * 4 + 2][j] = q1.x;
                c[hf * 4 + 3][j] = q1.y;
            }
    }
}

__global__ __attribute__((amdgpu_waves_per_eu(4, 4))) __launch_bounds__(256)
void fused_dcn(const float* __restrict__ x, const float* __restrict__ g,
               const float* __restrict__ ws_,
               const float* __restrict__ b_off, const float* __restrict__ b_mod,
               float* __restrict__ out) {
    __shared__ __align__(16) char Ubuf[144 * CPSTR * 2];  // 39168 B, unioned
    short* Wd = (short*)Ubuf;                 // conv window [144 pos][136]
    float* Xw = (float*)Ubuf;                 // deform window [240 pos][36]

    const int tid = threadIdx.x;
    const int l = tid & 63, lm = l & 15, quad = l >> 4;
    const int w = __builtin_amdgcn_readfirstlane(tid >> 6);   // wave = pixel row
    const int b = blockIdx.z;
    const int ho0 = blockIdx.y * 4, wo0 = blockIdx.x * 16;

    const short* at2 = (const short*)(ws_ + WB2_OFF);
    const short* atd = (const short*)(ws_ + WB_OFF);
    const float* xb = x + ((size_t)(b * Cc) << 14);
    const float* gb = g + ((size_t)(b * Cc) << 14);

    // ===================== conv phase (r4 structure) =======================
    {
        const int row_base = ho0 - 1;     // may be -1: halo rows zero-filled
        const int col_base = wo0 - 4;     // 4-aligned; halo cols zero-filled
        for (int s = tid; s < 1152; s += 256) {
            int pq = s >> 5, cq = s & 31;
            int r = pq / 6, c4 = (pq - r * 6) * 4;
            int row = row_base + r, col = col_base + c4;
            bool ok = ((unsigned)row < 128u) && ((unsigned)col < 128u);
            f32x4 v0, v1, v2, v3;
            {
                int ch = cq * 4;
                const float* p0 = (ch < Cc) ? (xb + ((size_t)ch << 14)) : (gb + ((size_t)(ch - Cc) << 14));
                const float* p1 = (ch + 1 < Cc) ? (xb + ((size_t)(ch + 1) << 14)) : (gb + ((size_t)(ch + 1 - Cc) << 14));
                const float* p2 = (ch + 2 < Cc) ? (xb + ((size_t)(ch + 2) << 14)) : (gb + ((size_t)(ch + 2 - Cc) << 14));
                const float* p3 = (ch + 3 < Cc) ? (xb + ((size_t)(ch + 3) << 14)) : (gb + ((size_t)(ch + 3 - Cc) << 14));
                f32x4 zz = {0.f, 0.f, 0.f, 0.f};
                size_t off = ((size_t)(row << 7) + col);
                v0 = ok ? *(const f32x4*)(p0 + off) : zz;
                v1 = ok ? *(const f32x4*)(p1 + off) : zz;
                v2 = ok ? *(const f32x4*)(p2 + off) : zz;
                v3 = ok ? *(const f32x4*)(p3 + off) : zz;
            }
#pragma unroll
            for (int p = 0; p < 4; p++) {
                s16x4 o4 = { f2bf(v0[p]), f2bf(v1[p]), f2bf(v2[p]), f2bf(v3[p]) };
                *(s16x4*)&Wd[(r * 24 + c4 + p) * CPSTR + cq * 4] = o4;
            }
        }
    }
    __syncthreads();

    f32x4 acc0 = {0.f, 0.f, 0.f, 0.f}, acc1 = {0.f, 0.f, 0.f, 0.f};
#pragma unroll
    for (int t = 0; t < 9; t++) {
        int dy = t / 3, dx = t - dy * 3;
        int pos = (w + dy) * 24 + (lm + dx + 3);
#pragma unroll
        for (int cc = 0; cc < 4; cc++) {
            bf16x8 bfr = *(const bf16x8*)&Wd[pos * CPSTR + cc * 32 + quad * 8];
            bf16x8 a0 = *(const bf16x8*)(at2 + t * 4096 + cc * 1024 + l * 8);
            bf16x8 a1 = *(const bf16x8*)(at2 + t * 4096 + cc * 1024 + 512 + l * 8);
            acc0 = __builtin_amdgcn_mfma_f32_16x16x32_bf16(a0, bfr, acc0, 0, 0, 0);
            acc1 = __builtin_amdgcn_mfma_f32_16x16x32_bf16(a1, bfr, acc1, 0, 0, 0);
        }
    }

    // -------- transforms (fused bias/coords/sigmoid), in-lane --------------
    // lane (quad,lm) holds j = mt*16 + quad*4 + reg for pixel (ho0+w, wo0+lm)
    const int ho = ho0 + w, wo = wo0 + lm;
    float tv[8];
#pragma unroll
    for (int mt = 0; mt < 2; mt++) {
        f32x4 a = mt ? acc1 : acc0;
#pragma unroll
        for (int reg = 0; reg < 4; reg++) {
            int j = mt * 16 + quad * 4 + reg;
            float v = a[reg];
            float r = 0.f;
            if (j < 18) {
                int k = j >> 1;
                float vb = v + b_off[j];
                r = (j & 1) ? (vb + (float)(k - (k / 3) * 3 + wo - 1))
                            : (vb + (float)(k / 3 + ho - 1));
            } else if (j < 27) {
                int k = j - 18;
                r = 2.f / (1.f + __expf(-(v + b_mod[k])));
            }
            tv[mt * 4 + reg] = r;
        }
    }

    // -------- 27 shuffles: every lane gets its pixel's 27 params -----------
    // pr[c]: c<9 py (j=2c), c<18 px (j=2(c-9)+1), else mask (j=c).
    float pr[27];
#pragma unroll
    for (int c = 0; c < 27; c++) {
        int j = (c < 9) ? (2 * c) : ((c < 18) ? (2 * (c - 9) + 1) : c);
        int srcLane = (((j >> 2) & 3) << 4) | lm;          // quad holding j, same lm
        pr[c] = __shfl(tv[(j >> 4) * 4 + (j & 3)], srcLane);
    }

    __syncthreads();   // all waves done reading Wd -> Xw may overwrite

    // ===================== deform phase (r6/r8 structure) ==================
    const int rb = min(max(ho0 - 3, 0), 128 - 10);
    const int cb = min(max(wo0 - 4, 0), 128 - 24);    // 4-aligned

    auto STAGE = [&](int h) {
        for (int s = tid; s < 480; s += 256) {
            int pq = s >> 3, cq = s & 7;
            int r = pq / 6, c4 = (pq - r * 6) * 4;
            size_t off = (size_t)((rb + r) << 7) + cb + c4;
            f32x4 v0 = *(const f32x4*)(xb + ((size_t)(h * 32 + cq * 4 + 0) << 14) + off);
            f32x4 v1 = *(const f32x4*)(xb + ((size_t)(h * 32 + cq * 4 + 1) << 14) + off);
            f32x4 v2 = *(const f32x4*)(xb + ((size_t)(h * 32 + cq * 4 + 2) << 14) + off);
            f32x4 v3 = *(const f32x4*)(xb + ((size_t)(h * 32 + cq * 4 + 3) << 14) + off);
#pragma unroll
            for (int p = 0; p < 4; p++) {
                f32x4 o4 = { v0[p], v1[p], v2[p], v3[p] };
                *(f32x4*)&Xw[(r * 24 + c4 + p) * DPSTR + cq * 4] = o4;
            }
        }
    };

    STAGE(0);
    __syncthreads();

    f32x4 acc[4];
#pragma unroll
    for (int mt = 0; mt < 4; mt++) acc[mt] = (f32x4){0.f, 0.f, 0.f, 0.f};

    auto T_LOOP = [&](int h) {
#pragma unroll
        for (int t = 0; t < 9; t++) {
            TapP P = tap_params_v(pr[t], pr[9 + t], pr[18 + t], rb, cb);
            f32x4 c[8];
            lds_corners(P, Xw, quad, c);
            fix_corners(P, xb, h, quad, c);
            union { short s8[8]; bf16x8 v; } u;
#pragma unroll
            for (int hf = 0; hf < 2; hf++)
#pragma unroll
                for (int j = 0; j < 4; j++)
                    u.s8[hf * 4 + j] = f2bf(P.wa0 * c[hf * 4 + 0][j] + P.wb0 * c[hf * 4 + 1][j] +
                                            P.wa1 * c[hf * 4 + 2][j] + P.wb1 * c[hf * 4 + 3][j]);
#pragma unroll
            for (int mt = 0; mt < 4; mt++) {
                bf16x8 a = *(const bf16x8*)(atd + t * 4096 + h * 2048 + mt * 512 + l * 8);
                acc[mt] = __builtin_amdgcn_mfma_f32_16x16x32_bf16(a, u.v, acc[mt], 0, 0, 0);
            }
        }
    };

    T_LOOP(0);
    __syncthreads();      // all waves done reading half 0
    STAGE(1);
    __syncthreads();
    T_LOOP(1);

    // Epilogue: D[row=quad*4+reg][col=lm]; o = mt*16+row, pixel = (ho, wo)
#pragma unroll
    for (int mt = 0; mt < 4; mt++) {
        float* op = out + ((size_t)(b * Oo + mt * 16 + quad * 4) << 14) + (ho << 7) + wo;
#pragma unroll
        for (int reg = 0; reg < 4; reg++)
            op[(size_t)reg << 14] = acc[mt][reg];
    }
}

// ---------------------------------------------------------------------------
extern "C" void kernel_launch(void* const* d_in, const int* in_sizes, int n_in,
                              void* d_out, int out_size, void* d_ws, size_t ws_size,
                              hipStream_t stream) {
    const float* x     = (const float*)d_in[0];
    const float* guide = (const float*)d_in[1];
    const float* w_off = (const float*)d_in[2];
    const float* b_off = (const float*)d_in[3];
    const float* w_mod = (const float*)d_in[4];
    const float* b_mod = (const float*)d_in[5];
    const float* w_reg = (const float*)d_in[6];
    float* out = (float*)d_out;
    float* ws  = (float*)d_ws;

    hipLaunchKernelGGL(prep_weights, dim3((73728 + 255) / 256), dim3(256),
                       0, stream, w_off, w_mod, w_reg, ws);
    hipLaunchKernelGGL(fused_dcn, dim3(Ww / 16, Hh / 4, Bn), dim3(256),
                       0, stream, x, guide, ws, b_off, b_mod, out);
}

// Round 10
// 140.718 us; speedup vs baseline: 1.1702x; 1.0938x over previous
//
#include <hip/hip_runtime.h>
#include <math.h>

// Problem constants
#define Bn   4
#define Cc   64
#define Hh   128
#define Ww   128
#define Oo   64
#define HW   16384
#define NPAR 27

// Workspace layout (float offsets)
#define WB2_OFF 0        // bf16 AT2[t][cc][mt2][lane64][8] = 36864 shorts
#define WB_OFF  18432    // bf16 ATd[t][h][mt4][lane64][8]  = 36864 shorts

typedef __attribute__((ext_vector_type(8))) short bf16x8;
typedef __attribute__((ext_vector_type(4))) short s16x4;
typedef __attribute__((ext_vector_type(4))) float f32x4;
typedef __attribute__((ext_vector_type(2), aligned(4))) float f32x2u;

__device__ __forceinline__ short f2bf(float f) {
    unsigned u = __builtin_bit_cast(unsigned, f);
    u += 0x7FFFu + ((u >> 16) & 1u);        // RNE
    return (short)(u >> 16);
}

// ---------------------------------------------------------------------------
// prep: pre-transpose weights into MFMA A-fragment order (unchanged from r4).
// ---------------------------------------------------------------------------
__global__ void prep_weights(const float* __restrict__ w_off,
                             const float* __restrict__ w_mod,
                             const float* __restrict__ w_reg,
                             float* __restrict__ ws) {
    int i = blockIdx.x * 256 + threadIdx.x;
    short* at2 = (short*)(ws + WB2_OFF);
    short* atd = (short*)(ws + WB_OFF);
    if (i < 36864) {
        int j = i & 7, l = (i >> 3) & 63, mt = (i >> 9) & 1, cc = (i >> 10) & 3, t = i >> 12;
        int lm = l & 15, quad = l >> 4;
        int row = mt * 16 + lm;
        int c = cc * 32 + quad * 8 + j;
        float v = 0.f;
        if (row < 18)      v = w_off[row * 1152 + c * 9 + t];
        else if (row < 27) v = w_mod[(row - 18) * 1152 + c * 9 + t];
        at2[i] = f2bf(v);
    } else if (i < 73728) {
        int e = i - 36864;
        int j = e & 7, l = (e >> 3) & 63, mt = (e >> 9) & 3, h = (e >> 11) & 1, t = e >> 12;
        int lm = l & 15, quad = l >> 4;
        int o = mt * 16 + lm;
        int c = h * 32 + quad * 8 + j;
        atd[e] = f2bf(w_reg[o * 576 + c * 9 + t]);
    }
}

// ---------------------------------------------------------------------------
// FUSED kernel round 10. r9 spilled (WRITE 69.6MB, VGPR=64): pr[27] in
// registers + 32-reg corner temps exceeded the 64-VGPR budget the allocator
// insists on (5 rounds of evidence: it will NOT allocate past ~64-68).
// Fixes, all pressure-side:
//  - par lives in LDS (parL[64px][29], 7.4KB; stride 29 odd -> reads are
//    broadcast x16-bank conflict-free). Lane ds_writes its 8 transformed
//    conv outputs; T_LOOP does 3 ds_read_b32 per tap. No pr[] registers.
//  - corners processed per-hf: 4 live vectors (16 VGPR) instead of 8 (32).
//  - deform window 10->8 rows so parL+Xw (35.1KB) fits under the conv
//    union (39.2KB) -> still 4 blocks/CU. Margin ~+-1px at extreme
//    row/tap; out-of-window lanes use the per-lane exec-masked global
//    fallback (identical math -> numerics unchanged).
// ---------------------------------------------------------------------------
#define CPSTR 136    // bf16 per conv pos: 128 ch + 8 pad
#define DPSTR 36     // f32 per deform pos: 32 ch + 4 pad
#define DROWS 8      // deform window rows
#define PAR_STR 29   // parL row stride (floats), odd -> conflict-free
#define XW_OFF (64 * PAR_STR)   // parL floats before Xw

struct TapP {
    float wa0, wb0, wa1, wb1;
    int ia, ib, gx0, gx1;
    bool in;
};

__device__ __forceinline__ TapP tap_params_v(float py, float px, float m,
                                             int rb, int cb) {
    float fy = floorf(py), fx = floorf(px);
    int y0 = (int)fy, x0 = (int)fx;
    int y1 = y0 + 1;
    float wy1 = py - fy, wx1 = px - fx;
    float wy0 = 1.f - wy1, wx0 = 1.f - wx1;
    bool vy0 = (unsigned)y0 < 128u, vy1 = (unsigned)y1 < 128u;
    bool vx0 = (unsigned)x0 < 128u, vx1 = (unsigned)(x0 + 1) < 128u;
    int cy0 = min(max(y0, 0), 127), cy1 = min(max(y1, 0), 127);
    int bx2 = min(max(x0, 0), 126);
    bool sel_lo = (x0 < 0), sel_hi = (x0 > 126);
    float w00 = (vy0 && vx0) ? wy0 * wx0 * m : 0.f;
    float w01 = (vy0 && vx1) ? wy0 * wx1 * m : 0.f;
    float w10 = (vy1 && vx0) ? wy1 * wx0 * m : 0.f;
    float w11 = (vy1 && vx1) ? wy1 * wx1 * m : 0.f;
    TapP r;
    // fold boundary handling into pair weights: wa->[bx2], wb->[bx2+1]
    r.wa0 = sel_lo ? w01 : (sel_hi ? 0.f : w00);
    r.wb0 = sel_hi ? w00 : (sel_lo ? 0.f : w01);
    r.wa1 = sel_lo ? w11 : (sel_hi ? 0.f : w10);
    r.wb1 = sel_hi ? w10 : (sel_lo ? 0.f : w11);
    int ty0 = cy0 - rb, ty1 = cy1 - rb, tx = bx2 - cb;
    r.ia = ty0 * 24 + tx;
    r.ib = ty1 * 24 + tx;
    r.gx0 = (cy0 << 7) + bx2;
    r.gx1 = (cy1 << 7) + bx2;
    r.in = ((unsigned)ty0 <= (unsigned)(DROWS - 1)) &&
           ((unsigned)ty1 <= (unsigned)(DROWS - 1)) &&
           ((unsigned)tx <= 22u);
    return r;
}

__global__ __launch_bounds__(256, 4)
void fused_dcn(const float* __restrict__ x, const float* __restrict__ g,
               const float* __restrict__ ws_,
               const float* __restrict__ b_off, const float* __restrict__ b_mod,
               float* __restrict__ out) {
    __shared__ __align__(16) char Ubuf[144 * CPSTR * 2];  // 39168 B, unioned
    short* Wd   = (short*)Ubuf;                // conv window [144 pos][136]
    float* parL = (float*)Ubuf;                // deform par [64 px][29]
    float* Xw   = (float*)Ubuf + XW_OFF;       // deform window [192 pos][36]

    const int tid = threadIdx.x;
    const int l = tid & 63, lm = l & 15, quad = l >> 4;
    const int w = __builtin_amdgcn_readfirstlane(tid >> 6);   // wave = pixel row
    const int b = blockIdx.z;
    const int ho0 = blockIdx.y * 4, wo0 = blockIdx.x * 16;

    const short* at2 = (const short*)(ws_ + WB2_OFF);
    const short* atd = (const short*)(ws_ + WB_OFF);
    const float* xb = x + ((size_t)(b * Cc) << 14);
    const float* gb = g + ((size_t)(b * Cc) << 14);

    // ===================== conv phase (r4 structure) =======================
    {
        const int row_base = ho0 - 1;     // may be -1: halo rows zero-filled
        const int col_base = wo0 - 4;     // 4-aligned; halo cols zero-filled
        for (int s = tid; s < 1152; s += 256) {
            int pq = s >> 5, cq = s & 31;
            int r = pq / 6, c4 = (pq - r * 6) * 4;
            int row = row_base + r, col = col_base + c4;
            bool ok = ((unsigned)row < 128u) && ((unsigned)col < 128u);
            f32x4 v0, v1, v2, v3;
            {
                int ch = cq * 4;
                const float* p0 = (ch < Cc) ? (xb + ((size_t)ch << 14)) : (gb + ((size_t)(ch - Cc) << 14));
                const float* p1 = (ch + 1 < Cc) ? (xb + ((size_t)(ch + 1) << 14)) : (gb + ((size_t)(ch + 1 - Cc) << 14));
                const float* p2 = (ch + 2 < Cc) ? (xb + ((size_t)(ch + 2) << 14)) : (gb + ((size_t)(ch + 2 - Cc) << 14));
                const float* p3 = (ch + 3 < Cc) ? (xb + ((size_t)(ch + 3) << 14)) : (gb + ((size_t)(ch + 3 - Cc) << 14));
                f32x4 zz = {0.f, 0.f, 0.f, 0.f};
                size_t off = ((size_t)(row << 7) + col);
                v0 = ok ? *(const f32x4*)(p0 + off) : zz;
                v1 = ok ? *(const f32x4*)(p1 + off) : zz;
                v2 = ok ? *(const f32x4*)(p2 + off) : zz;
                v3 = ok ? *(const f32x4*)(p3 + off) : zz;
            }
#pragma unroll
            for (int p = 0; p < 4; p++) {
                s16x4 o4 = { f2bf(v0[p]), f2bf(v1[p]), f2bf(v2[p]), f2bf(v3[p]) };
                *(s16x4*)&Wd[(r * 24 + c4 + p) * CPSTR + cq * 4] = o4;
            }
        }
    }
    __syncthreads();

    f32x4 acc0 = {0.f, 0.f, 0.f, 0.f}, acc1 = {0.f, 0.f, 0.f, 0.f};
#pragma unroll
    for (int t = 0; t < 9; t++) {
        int dy = t / 3, dx = t - dy * 3;
        int pos = (w + dy) * 24 + (lm + dx + 3);
#pragma unroll
        for (int cc = 0; cc < 4; cc++) {
            bf16x8 bfr = *(const bf16x8*)&Wd[pos * CPSTR + cc * 32 + quad * 8];
            bf16x8 a0 = *(const bf16x8*)(at2 + t * 4096 + cc * 1024 + l * 8);
            bf16x8 a1 = *(const bf16x8*)(at2 + t * 4096 + cc * 1024 + 512 + l * 8);
            acc0 = __builtin_amdgcn_mfma_f32_16x16x32_bf16(a0, bfr, acc0, 0, 0, 0);
            acc1 = __builtin_amdgcn_mfma_f32_16x16x32_bf16(a1, bfr, acc1, 0, 0, 0);
        }
    }

    // -------- transforms (bias/coords/sigmoid) in registers ---------------
    // lane (quad,lm) holds j = mt*16 + quad*4 + reg for pixel (ho0+w, wo0+lm)
    const int ho = ho0 + w, wo = wo0 + lm;
    const int pxi = w * 16 + lm;               // pixel index in tile, 0..63
    float tr[8];
#pragma unroll
    for (int mt = 0; mt < 2; mt++) {
        f32x4 a = mt ? acc1 : acc0;
#pragma unroll
        for (int reg = 0; reg < 4; reg++) {
            int j = mt * 16 + quad * 4 + reg;
            float v = a[reg];
            float r = 0.f;
            if (j < 18) {
                int k = j >> 1;
                float vb = v + b_off[j];
                r = (j & 1) ? (vb + (float)(k - (k / 3) * 3 + wo - 1))
                            : (vb + (float)(k / 3 + ho - 1));
            } else if (j < 27) {
                int k = j - 18;
                r = 2.f / (1.f + __expf(-(v + b_mod[k])));
            }
            tr[mt * 4 + reg] = r;
        }
    }

    __syncthreads();   // all waves done reading Wd -> parL/Xw may overwrite

    // -------- par -> LDS: channel c; c<9 py(j=2c), 9..17 px, 18..26 mask ---
#pragma unroll
    for (int mt = 0; mt < 2; mt++)
#pragma unroll
        for (int reg = 0; reg < 4; reg++) {
            int j = mt * 16 + quad * 4 + reg;
            if (j < 27) {
                int c = (j < 18) ? ((j & 1) ? (9 + (j >> 1)) : (j >> 1)) : j;
                parL[pxi * PAR_STR + c] = tr[mt * 4 + reg];
            }
        }

    // ===================== deform phase ====================================
    const int rb = min(max(ho0 - 2, 0), 128 - DROWS);
    const int cb = min(max(wo0 - 4, 0), 128 - 24);    // 4-aligned

    auto STAGE = [&](int h) {
        for (int s = tid; s < DROWS * 6 * 8; s += 256) {
            int pq = s >> 3, cq = s & 7;
            int r = pq / 6, c4 = (pq - r * 6) * 4;
            size_t off = (size_t)((rb + r) << 7) + cb + c4;
            f32x4 v0 = *(const f32x4*)(xb + ((size_t)(h * 32 + cq * 4 + 0) << 14) + off);
            f32x4 v1 = *(const f32x4*)(xb + ((size_t)(h * 32 + cq * 4 + 1) << 14) + off);
            f32x4 v2 = *(const f32x4*)(xb + ((size_t)(h * 32 + cq * 4 + 2) << 14) + off);
            f32x4 v3 = *(const f32x4*)(xb + ((size_t)(h * 32 + cq * 4 + 3) << 14) + off);
#pragma unroll
            for (int p = 0; p < 4; p++) {
                f32x4 o4 = { v0[p], v1[p], v2[p], v3[p] };
                *(f32x4*)&Xw[(r * 24 + c4 + p) * DPSTR + cq * 4] = o4;
            }
        }
    };

    STAGE(0);
    __syncthreads();

    f32x4 acc[4];
#pragma unroll
    for (int mt = 0; mt < 4; mt++) acc[mt] = (f32x4){0.f, 0.f, 0.f, 0.f};

    auto T_LOOP = [&](int h) {
#pragma unroll
        for (int t = 0; t < 9; t++) {
            float py = parL[pxi * PAR_STR + t];
            float px = parL[pxi * PAR_STR + 9 + t];
            float m  = parL[pxi * PAR_STR + 18 + t];
            TapP P = tap_params_v(py, px, m, rb, cb);
            int ia = min(max(P.ia, 0), DROWS * 24 - 2);
            int ib = min(max(P.ib, 0), DROWS * 24 - 2);
            union { short s8[8]; bf16x8 v; } u;
#pragma unroll
            for (int hf = 0; hf < 2; hf++) {
                const float* pa = Xw + ia * DPSTR + quad * 8 + hf * 4;
                const float* pb = Xw + ib * DPSTR + quad * 8 + hf * 4;
                f32x4 c0 = *(const f32x4*)(pa);
                f32x4 c1 = *(const f32x4*)(pa + DPSTR);
                f32x4 c2 = *(const f32x4*)(pb);
                f32x4 c3 = *(const f32x4*)(pb + DPSTR);
                if (__builtin_expect(!P.in, 0)) {   // rare per-lane patch
#pragma unroll
                    for (int j = 0; j < 4; j++) {
                        int cch = h * 32 + quad * 8 + hf * 4 + j;
                        const float* xc = xb + ((size_t)cch << 14);
                        f32x2u q0 = *(const f32x2u*)(xc + P.gx0);
                        f32x2u q1 = *(const f32x2u*)(xc + P.gx1);
                        c0[j] = q0.x; c1[j] = q0.y; c2[j] = q1.x; c3[j] = q1.y;
                    }
                }
#pragma unroll
                for (int j = 0; j < 4; j++)
                    u.s8[hf * 4 + j] = f2bf(P.wa0 * c0[j] + P.wb0 * c1[j] +
                                            P.wa1 * c2[j] + P.wb1 * c3[j]);
            }
#pragma unroll
            for (int mt = 0; mt < 4; mt++) {
                bf16x8 a = *(const bf16x8*)(atd + t * 4096 + h * 2048 + mt * 512 + l * 8);
                acc[mt] = __builtin_amdgcn_mfma_f32_16x16x32_bf16(a, u.v, acc[mt], 0, 0, 0);
            }
        }
    };

    T_LOOP(0);
    __syncthreads();      // all waves done reading half-0 window
    STAGE(1);             // overwrites Xw only; parL untouched
    __syncthreads();
    T_LOOP(1);

    // Epilogue: D[row=quad*4+reg][col=lm]; o = mt*16+row, pixel = (ho, wo)
#pragma unroll
    for (int mt = 0; mt < 4; mt++) {
        float* op = out + ((size_t)(b * Oo + mt * 16 + quad * 4) << 14) + (ho << 7) + wo;
#pragma unroll
        for (int reg = 0; reg < 4; reg++)
            op[(size_t)reg << 14] = acc[mt][reg];
    }
}

// ---------------------------------------------------------------------------
extern "C" void kernel_launch(void* const* d_in, const int* in_sizes, int n_in,
                              void* d_out, int out_size, void* d_ws, size_t ws_size,
                              hipStream_t stream) {
    const float* x     = (const float*)d_in[0];
    const float* guide = (const float*)d_in[1];
    const float* w_off = (const float*)d_in[2];
    const float* b_off = (const float*)d_in[3];
    const float* w_mod = (const float*)d_in[4];
    const float* b_mod = (const float*)d_in[5];
    const float* w_reg = (const float*)d_in[6];
    float* out = (float*)d_out;
    float* ws  = (float*)d_ws;

    hipLaunchKernelGGL(prep_weights, dim3((73728 + 255) / 256), dim3(256),
                       0, stream, w_off, w_mod, w_reg, ws);
    hipLaunchKernelGGL(fused_dcn, dim3(Ww / 16, Hh / 4, Bn), dim3(256),
                       0, stream, x, guide, ws, b_off, b_mod, out);
}

// Round 11
// 127.410 us; speedup vs baseline: 1.2924x; 1.1045x over previous
//
#include <hip/hip_runtime.h>
#include <math.h>

// Problem constants
#define Bn   4
#define Cc   64
#define Hh   128
#define Ww   128
#define Oo   64
#define HW   16384
#define NPAR 27

// Workspace layout (float offsets)
#define WB2_OFF 0        // bf16 AT2[t][cc][mt2][lane64][8] = 36864 shorts
#define WB_OFF  18432    // bf16 ATd[t][h][mt4][lane64][8]  = 36864 shorts

typedef __attribute__((ext_vector_type(8))) short bf16x8;
typedef __attribute__((ext_vector_type(4))) short s16x4;
typedef __attribute__((ext_vector_type(4))) float f32x4;
typedef __attribute__((ext_vector_type(2), aligned(4))) float f32x2u;

__device__ __forceinline__ short f2bf(float f) {
    unsigned u = __builtin_bit_cast(unsigned, f);
    u += 0x7FFFu + ((u >> 16) & 1u);        // RNE
    return (short)(u >> 16);
}

// ---------------------------------------------------------------------------
// prep: pre-transpose weights into MFMA A-fragment order (unchanged from r4).
// ---------------------------------------------------------------------------
__global__ void prep_weights(const float* __restrict__ w_off,
                             const float* __restrict__ w_mod,
                             const float* __restrict__ w_reg,
                             float* __restrict__ ws) {
    int i = blockIdx.x * 256 + threadIdx.x;
    short* at2 = (short*)(ws + WB2_OFF);
    short* atd = (short*)(ws + WB_OFF);
    if (i < 36864) {
        int j = i & 7, l = (i >> 3) & 63, mt = (i >> 9) & 1, cc = (i >> 10) & 3, t = i >> 12;
        int lm = l & 15, quad = l >> 4;
        int row = mt * 16 + lm;
        int c = cc * 32 + quad * 8 + j;
        float v = 0.f;
        if (row < 18)      v = w_off[row * 1152 + c * 9 + t];
        else if (row < 27) v = w_mod[(row - 18) * 1152 + c * 9 + t];
        at2[i] = f2bf(v);
    } else if (i < 73728) {
        int e = i - 36864;
        int j = e & 7, l = (e >> 3) & 63, mt = (e >> 9) & 3, h = (e >> 11) & 1, t = e >> 12;
        int lm = l & 15, quad = l >> 4;
        int o = mt * 16 + lm;
        int c = h * 32 + quad * 8 + j;
        atd[e] = f2bf(w_reg[o * 576 + c * 9 + t]);
    }
}

// ---------------------------------------------------------------------------
// FUSED kernel round 11 = r10 + XCD-aware block swizzle (T1).
// r10 landed clean (WRITE=16384, VGPR=52, 63.2us) but FETCH=124.5MB vs
// ~50MB ideal: halo/window re-reads miss L2 because consecutive blocks
// round-robin across 8 XCDs (per-XCD working set = whole image, 33.5MB
// >> 4MB L2). Swizzle gives each XCD a contiguous 128-block chunk (half a
// batch image); its 128 co-resident blocks' footprint ~4.3MB ~ L2 ->
// halo + deform re-stage reads become L2 hits (~200cy vs ~900cy).
// nwg=1024 % 8 == 0 -> simple bijection swz=(bid&7)*128 + (bid>>3).
// Nothing else changed from r10.
// ---------------------------------------------------------------------------
#define CPSTR 136    // bf16 per conv pos: 128 ch + 8 pad
#define DPSTR 36     // f32 per deform pos: 32 ch + 4 pad
#define DROWS 8      // deform window rows
#define PAR_STR 29   // parL row stride (floats), odd -> conflict-free
#define XW_OFF (64 * PAR_STR)   // parL floats before Xw

struct TapP {
    float wa0, wb0, wa1, wb1;
    int ia, ib, gx0, gx1;
    bool in;
};

__device__ __forceinline__ TapP tap_params_v(float py, float px, float m,
                                             int rb, int cb) {
    float fy = floorf(py), fx = floorf(px);
    int y0 = (int)fy, x0 = (int)fx;
    int y1 = y0 + 1;
    float wy1 = py - fy, wx1 = px - fx;
    float wy0 = 1.f - wy1, wx0 = 1.f - wx1;
    bool vy0 = (unsigned)y0 < 128u, vy1 = (unsigned)y1 < 128u;
    bool vx0 = (unsigned)x0 < 128u, vx1 = (unsigned)(x0 + 1) < 128u;
    int cy0 = min(max(y0, 0), 127), cy1 = min(max(y1, 0), 127);
    int bx2 = min(max(x0, 0), 126);
    bool sel_lo = (x0 < 0), sel_hi = (x0 > 126);
    float w00 = (vy0 && vx0) ? wy0 * wx0 * m : 0.f;
    float w01 = (vy0 && vx1) ? wy0 * wx1 * m : 0.f;
    float w10 = (vy1 && vx0) ? wy1 * wx0 * m : 0.f;
    float w11 = (vy1 && vx1) ? wy1 * wx1 * m : 0.f;
    TapP r;
    // fold boundary handling into pair weights: wa->[bx2], wb->[bx2+1]
    r.wa0 = sel_lo ? w01 : (sel_hi ? 0.f : w00);
    r.wb0 = sel_hi ? w00 : (sel_lo ? 0.f : w01);
    r.wa1 = sel_lo ? w11 : (sel_hi ? 0.f : w10);
    r.wb1 = sel_hi ? w10 : (sel_lo ? 0.f : w11);
    int ty0 = cy0 - rb, ty1 = cy1 - rb, tx = bx2 - cb;
    r.ia = ty0 * 24 + tx;
    r.ib = ty1 * 24 + tx;
    r.gx0 = (cy0 << 7) + bx2;
    r.gx1 = (cy1 << 7) + bx2;
    r.in = ((unsigned)ty0 <= (unsigned)(DROWS - 1)) &&
           ((unsigned)ty1 <= (unsigned)(DROWS - 1)) &&
           ((unsigned)tx <= 22u);
    return r;
}

__global__ __launch_bounds__(256, 4)
void fused_dcn(const float* __restrict__ x, const float* __restrict__ g,
               const float* __restrict__ ws_,
               const float* __restrict__ b_off, const float* __restrict__ b_mod,
               float* __restrict__ out) {
    __shared__ __align__(16) char Ubuf[144 * CPSTR * 2];  // 39168 B, unioned
    short* Wd   = (short*)Ubuf;                // conv window [144 pos][136]
    float* parL = (float*)Ubuf;                // deform par [64 px][29]
    float* Xw   = (float*)Ubuf + XW_OFF;       // deform window [192 pos][36]

    const int tid = threadIdx.x;
    const int l = tid & 63, lm = l & 15, quad = l >> 4;
    const int w = __builtin_amdgcn_readfirstlane(tid >> 6);   // wave = pixel row

    // XCD-aware swizzle: HW round-robins original bid over 8 XCDs; remap so
    // XCD k owns tiles [k*128, (k+1)*128) = a contiguous half-image chunk.
    const int bid = ((blockIdx.z << 5) + blockIdx.y) * 8 + blockIdx.x;  // grid (8,32,4)
    const int swz = ((bid & 7) << 7) | (bid >> 3);                      // bijective, 1024
    const int tx_ = swz & 7, ty_ = (swz >> 3) & 31, b = swz >> 8;
    const int ho0 = ty_ * 4, wo0 = tx_ * 16;

    const short* at2 = (const short*)(ws_ + WB2_OFF);
    const short* atd = (const short*)(ws_ + WB_OFF);
    const float* xb = x + ((size_t)(b * Cc) << 14);
    const float* gb = g + ((size_t)(b * Cc) << 14);

    // ===================== conv phase (r4 structure) =======================
    {
        const int row_base = ho0 - 1;     // may be -1: halo rows zero-filled
        const int col_base = wo0 - 4;     // 4-aligned; halo cols zero-filled
        for (int s = tid; s < 1152; s += 256) {
            int pq = s >> 5, cq = s & 31;
            int r = pq / 6, c4 = (pq - r * 6) * 4;
            int row = row_base + r, col = col_base + c4;
            bool ok = ((unsigned)row < 128u) && ((unsigned)col < 128u);
            f32x4 v0, v1, v2, v3;
            {
                int ch = cq * 4;
                const float* p0 = (ch < Cc) ? (xb + ((size_t)ch << 14)) : (gb + ((size_t)(ch - Cc) << 14));
                const float* p1 = (ch + 1 < Cc) ? (xb + ((size_t)(ch + 1) << 14)) : (gb + ((size_t)(ch + 1 - Cc) << 14));
                const float* p2 = (ch + 2 < Cc) ? (xb + ((size_t)(ch + 2) << 14)) : (gb + ((size_t)(ch + 2 - Cc) << 14));
                const float* p3 = (ch + 3 < Cc) ? (xb + ((size_t)(ch + 3) << 14)) : (gb + ((size_t)(ch + 3 - Cc) << 14));
                f32x4 zz = {0.f, 0.f, 0.f, 0.f};
                size_t off = ((size_t)(row << 7) + col);
                v0 = ok ? *(const f32x4*)(p0 + off) : zz;
                v1 = ok ? *(const f32x4*)(p1 + off) : zz;
                v2 = ok ? *(const f32x4*)(p2 + off) : zz;
                v3 = ok ? *(const f32x4*)(p3 + off) : zz;
            }
#pragma unroll
            for (int p = 0; p < 4; p++) {
                s16x4 o4 = { f2bf(v0[p]), f2bf(v1[p]), f2bf(v2[p]), f2bf(v3[p]) };
                *(s16x4*)&Wd[(r * 24 + c4 + p) * CPSTR + cq * 4] = o4;
            }
        }
    }
    __syncthreads();

    f32x4 acc0 = {0.f, 0.f, 0.f, 0.f}, acc1 = {0.f, 0.f, 0.f, 0.f};
#pragma unroll
    for (int t = 0; t < 9; t++) {
        int dy = t / 3, dx = t - dy * 3;
        int pos = (w + dy) * 24 + (lm + dx + 3);
#pragma unroll
        for (int cc = 0; cc < 4; cc++) {
            bf16x8 bfr = *(const bf16x8*)&Wd[pos * CPSTR + cc * 32 + quad * 8];
            bf16x8 a0 = *(const bf16x8*)(at2 + t * 4096 + cc * 1024 + l * 8);
            bf16x8 a1 = *(const bf16x8*)(at2 + t * 4096 + cc * 1024 + 512 + l * 8);
            acc0 = __builtin_amdgcn_mfma_f32_16x16x32_bf16(a0, bfr, acc0, 0, 0, 0);
            acc1 = __builtin_amdgcn_mfma_f32_16x16x32_bf16(a1, bfr, acc1, 0, 0, 0);
        }
    }

    // -------- transforms (bias/coords/sigmoid) in registers ---------------
    // lane (quad,lm) holds j = mt*16 + quad*4 + reg for pixel (ho0+w, wo0+lm)
    const int ho = ho0 + w, wo = wo0 + lm;
    const int pxi = w * 16 + lm;               // pixel index in tile, 0..63
    float tr[8];
#pragma unroll
    for (int mt = 0; mt < 2; mt++) {
        f32x4 a = mt ? acc1 : acc0;
#pragma unroll
        for (int reg = 0; reg < 4; reg++) {
            int j = mt * 16 + quad * 4 + reg;
            float v = a[reg];
            float r = 0.f;
            if (j < 18) {
                int k = j >> 1;
                float vb = v + b_off[j];
                r = (j & 1) ? (vb + (float)(k - (k / 3) * 3 + wo - 1))
                            : (vb + (float)(k / 3 + ho - 1));
            } else if (j < 27) {
                int k = j - 18;
                r = 2.f / (1.f + __expf(-(v + b_mod[k])));
            }
            tr[mt * 4 + reg] = r;
        }
    }

    __syncthreads();   // all waves done reading Wd -> parL/Xw may overwrite

    // -------- par -> LDS: channel c; c<9 py(j=2c), 9..17 px, 18..26 mask ---
#pragma unroll
    for (int mt = 0; mt < 2; mt++)
#pragma unroll
        for (int reg = 0; reg < 4; reg++) {
            int j = mt * 16 + quad * 4 + reg;
            if (j < 27) {
                int c = (j < 18) ? ((j & 1) ? (9 + (j >> 1)) : (j >> 1)) : j;
                parL[pxi * PAR_STR + c] = tr[mt * 4 + reg];
            }
        }

    // ===================== deform phase ====================================
    const int rb = min(max(ho0 - 2, 0), 128 - DROWS);
    const int cb = min(max(wo0 - 4, 0), 128 - 24);    // 4-aligned

    auto STAGE = [&](int h) {
        for (int s = tid; s < DROWS * 6 * 8; s += 256) {
            int pq = s >> 3, cq = s & 7;
            int r = pq / 6, c4 = (pq - r * 6) * 4;
            size_t off = (size_t)((rb + r) << 7) + cb + c4;
            f32x4 v0 = *(const f32x4*)(xb + ((size_t)(h * 32 + cq * 4 + 0) << 14) + off);
            f32x4 v1 = *(const f32x4*)(xb + ((size_t)(h * 32 + cq * 4 + 1) << 14) + off);
            f32x4 v2 = *(const f32x4*)(xb + ((size_t)(h * 32 + cq * 4 + 2) << 14) + off);
            f32x4 v3 = *(const f32x4*)(xb + ((size_t)(h * 32 + cq * 4 + 3) << 14) + off);
#pragma unroll
            for (int p = 0; p < 4; p++) {
                f32x4 o4 = { v0[p], v1[p], v2[p], v3[p] };
                *(f32x4*)&Xw[(r * 24 + c4 + p) * DPSTR + cq * 4] = o4;
            }
        }
    };

    STAGE(0);
    __syncthreads();

    f32x4 acc[4];
#pragma unroll
    for (int mt = 0; mt < 4; mt++) acc[mt] = (f32x4){0.f, 0.f, 0.f, 0.f};

    auto T_LOOP = [&](int h) {
#pragma unroll
        for (int t = 0; t < 9; t++) {
            float py = parL[pxi * PAR_STR + t];
            float px = parL[pxi * PAR_STR + 9 + t];
            float m  = parL[pxi * PAR_STR + 18 + t];
            TapP P = tap_params_v(py, px, m, rb, cb);
            int ia = min(max(P.ia, 0), DROWS * 24 - 2);
            int ib = min(max(P.ib, 0), DROWS * 24 - 2);
            union { short s8[8]; bf16x8 v; } u;
#pragma unroll
            for (int hf = 0; hf < 2; hf++) {
                const float* pa = Xw + ia * DPSTR + quad * 8 + hf * 4;
                const float* pb = Xw + ib * DPSTR + quad * 8 + hf * 4;
                f32x4 c0 = *(const f32x4*)(pa);
                f32x4 c1 = *(const f32x4*)(pa + DPSTR);
                f32x4 c2 = *(const f32x4*)(pb);
                f32x4 c3 = *(const f32x4*)(pb + DPSTR);
                if (__builtin_expect(!P.in, 0)) {   // rare per-lane patch
#pragma unroll
                    for (int j = 0; j < 4; j++) {
                        int cch = h * 32 + quad * 8 + hf * 4 + j;
                        const float* xc = xb + ((size_t)cch << 14);
                        f32x2u q0 = *(const f32x2u*)(xc + P.gx0);
                        f32x2u q1 = *(const f32x2u*)(xc + P.gx1);
                        c0[j] = q0.x; c1[j] = q0.y; c2[j] = q1.x; c3[j] = q1.y;
                    }
                }
#pragma unroll
                for (int j = 0; j < 4; j++)
                    u.s8[hf * 4 + j] = f2bf(P.wa0 * c0[j] + P.wb0 * c1[j] +
                                            P.wa1 * c2[j] + P.wb1 * c3[j]);
            }
#pragma unroll
            for (int mt = 0; mt < 4; mt++) {
                bf16x8 a = *(const bf16x8*)(atd + t * 4096 + h * 2048 + mt * 512 + l * 8);
                acc[mt] = __builtin_amdgcn_mfma_f32_16x16x32_bf16(a, u.v, acc[mt], 0, 0, 0);
            }
        }
    };

    T_LOOP(0);
    __syncthreads();      // all waves done reading half-0 window
    STAGE(1);             // overwrites Xw only; parL untouched
    __syncthreads();
    T_LOOP(1);

    // Epilogue: D[row=quad*4+reg][col=lm]; o = mt*16+row, pixel = (ho, wo)
#pragma unroll
    for (int mt = 0; mt < 4; mt++) {
        float* op = out + ((size_t)(b * Oo + mt * 16 + quad * 4) << 14) + (ho << 7) + wo;
#pragma unroll
        for (int reg = 0; reg < 4; reg++)
            op[(size_t)reg << 14] = acc[mt][reg];
    }
}

// ---------------------------------------------------------------------------
extern "C" void kernel_launch(void* const* d_in, const int* in_sizes, int n_in,
                              void* d_out, int out_size, void* d_ws, size_t ws_size,
                              hipStream_t stream) {
    const float* x     = (const float*)d_in[0];
    const float* guide = (const float*)d_in[1];
    const float* w_off = (const float*)d_in[2];
    const float* b_off = (const float*)d_in[3];
    const float* w_mod = (const float*)d_in[4];
    const float* b_mod = (const float*)d_in[5];
    const float* w_reg = (const float*)d_in[6];
    float* out = (float*)d_out;
    float* ws  = (float*)d_ws;

    hipLaunchKernelGGL(prep_weights, dim3((73728 + 255) / 256), dim3(256),
                       0, stream, w_off, w_mod, w_reg, ws);
    hipLaunchKernelGGL(fused_dcn, dim3(Ww / 16, Hh / 4, Bn), dim3(256),
                       0, stream, x, guide, ws, b_off, b_mod, out);
}